// Round 9
// baseline (180.964 us; speedup 1.0000x reference)
//
#include <hip/hip_runtime.h>
#include <stdint.h>

// ShuffledGroupWhitening on MI355X.
// x: [3*8192, 1024] f32, perms: [3,1024] i32.
// Per (view s, group g): gather 16 permuted cols, center over batch,
// whiten with cov^{-1/2} (Newton-Schulz), scatter back (same col set).
//
// R8 -> R9: stats was latency-bound (22% occupancy, clean traffic). Same
// direct-gather structure, but 512-thread blocks: half A (tid<256) does rows
// 0-15, half B rows 16-31, 4-row unroll (16 gathers in flight/wave), then a
// 5-round LDS reduction folds B into A before the single partial write.
// 24 waves/CU co-resident (2x TLP), partials traffic unchanged (53.5 MB).

constexpr int D_FEAT  = 1024;
constexpr int NGROUP  = 64;
constexpr int GD      = 16;     // group dim
constexpr int NB      = 8192;   // rows per view
constexpr int NVIEW   = 3;

constexpr int P1      = 256;    // stats blocks per view (768 total = 3/CU)
constexpr int RPP1    = NB / P1;        // 32 rows per stats block
constexpr int HROWS   = RPP1 / 2;       // 16 rows per half
constexpr int RPB3    = 32;     // rows per apply block
constexpr int C3      = 4;      // chunk rows (apply)
constexpr int PSPLIT  = 8;      // reduce split factor

constexpr int SXX_FLOATS  = NGROUP * GD * GD;        // 16384 per view
constexpr int PART_STRIDE = SXX_FLOATS + D_FEAT;     // 17408 per partial
constexpr int ENT         = NVIEW * PART_STRIDE;     // 52224 stat entries

// ws layout (floats) — partials live in d_out, NOT here
constexpr int SXX_OFF = 0;                           // [3][64][16][16]
constexpr int SX_OFF  = NVIEW * SXX_FLOATS;          // 49152: [3][1024]
constexpr int W_OFF   = SX_OFF + NVIEW * D_FEAT;     // 52224: [3][64][16][16]
constexpr int RED_OFF = W_OFF + NVIEW * SXX_FLOATS;  // 101376: [8][52224]
// total ws use = RED_OFF + PSPLIT*ENT = 519168 floats ~ 2.1 MB

// quad broadcast: every lane gets lane ((lane&~3)+B)'s value. Pure VALU DPP.
template <int B>
__device__ __forceinline__ float qbc(float x) {
    return __int_as_float(__builtin_amdgcn_mov_dpp(
        __float_as_int(x), B * 0x55 /*quad_perm[B,B,B,B]*/, 0xF, 0xF, true));
}

// ---------------- Pass 1a: per-block partial Sxx and Sx ----------------
// 512 threads; slot lt = tid&255 owns quad (g = lt>>2, q = lt&3); half = tid>>8
// processes 16 of the block's 32 rows. Direct global gathers (block reads whole
// rows -> L2/L3 absorb line overlap), DPP rebuilds v[16], LDS-reduce halves.
__global__ __launch_bounds__(512, 6) void k_stats_gather(const float* __restrict__ x,
                                                         const int* __restrict__ perms,
                                                         float* __restrict__ part) {
    __shared__ float red[256][17];                   // 17.4 KB, stride-17 (conflict-light)
    const int s    = blockIdx.y;
    const int p    = blockIdx.x;
    const int tid  = threadIdx.x;
    const int lt   = tid & 255;
    const int half = tid >> 8;

    int pcolq[4];
#pragma unroll
    for (int jj = 0; jj < 4; ++jj) pcolq[jj] = perms[s * D_FEAT + lt * 4 + jj];

    float acc[GD][4];
#pragma unroll
    for (int i = 0; i < GD; ++i)
#pragma unroll
        for (int jj = 0; jj < 4; ++jj) acc[i][jj] = 0.0f;
    float sacc[4] = {0.0f, 0.0f, 0.0f, 0.0f};

    const float* xbase = x + (size_t)(s * NB + p * RPP1 + half * HROWS) * D_FEAT;

// accumulate one row given its 4 gathered quad values
#define ROW_ACC(Q0, Q1, Q2, Q3)                                                \
    {                                                                          \
        float vq_[4] = {Q0, Q1, Q2, Q3};                                       \
        float v_[GD];                                                          \
        _Pragma("unroll")                                                      \
        for (int jj = 0; jj < 4; ++jj) {                                       \
            v_[0  + jj] = qbc<0>(vq_[jj]);                                     \
            v_[4  + jj] = qbc<1>(vq_[jj]);                                     \
            v_[8  + jj] = qbc<2>(vq_[jj]);                                     \
            v_[12 + jj] = qbc<3>(vq_[jj]);                                     \
        }                                                                      \
        _Pragma("unroll")                                                      \
        for (int jj = 0; jj < 4; ++jj) sacc[jj] += vq_[jj];                    \
        _Pragma("unroll")                                                      \
        for (int i = 0; i < GD; ++i)                                           \
            _Pragma("unroll")                                                  \
            for (int jj = 0; jj < 4; ++jj)                                     \
                acc[i][jj] = fmaf(v_[i], vq_[jj], acc[i][jj]);                 \
    }

    // 4 rows per iteration: 16 independent dword gathers in flight per wave.
    for (int r = 0; r < HROWS; r += 4) {
        const float* r0 = xbase + (size_t)r * D_FEAT;
        const float* r1 = r0 + D_FEAT;
        const float* r2 = r1 + D_FEAT;
        const float* r3 = r2 + D_FEAT;
        const float a0 = r0[pcolq[0]], a1 = r0[pcolq[1]],
                    a2 = r0[pcolq[2]], a3 = r0[pcolq[3]];
        const float b0 = r1[pcolq[0]], b1 = r1[pcolq[1]],
                    b2 = r1[pcolq[2]], b3 = r1[pcolq[3]];
        const float c0 = r2[pcolq[0]], c1 = r2[pcolq[1]],
                    c2 = r2[pcolq[2]], c3 = r2[pcolq[3]];
        const float d0 = r3[pcolq[0]], d1 = r3[pcolq[1]],
                    d2 = r3[pcolq[2]], d3 = r3[pcolq[3]];
        ROW_ACC(a0, a1, a2, a3)
        ROW_ACC(b0, b1, b2, b3)
        ROW_ACC(c0, c1, c2, c3)
        ROW_ACC(d0, d1, d2, d3)
    }
#undef ROW_ACC

    // fold half B into half A: 4 rounds of 4 acc-rows + 1 round of sacc
#pragma unroll
    for (int i0 = 0; i0 < GD; i0 += 4) {
        __syncthreads();                             // buffer free
        if (half) {
#pragma unroll
            for (int i = 0; i < 4; ++i)
#pragma unroll
                for (int jj = 0; jj < 4; ++jj)
                    red[lt][i * 4 + jj] = acc[i0 + i][jj];
        }
        __syncthreads();
        if (!half) {
#pragma unroll
            for (int i = 0; i < 4; ++i)
#pragma unroll
                for (int jj = 0; jj < 4; ++jj)
                    acc[i0 + i][jj] += red[lt][i * 4 + jj];
        }
    }
    __syncthreads();
    if (half) {
#pragma unroll
        for (int jj = 0; jj < 4; ++jj) red[lt][jj] = sacc[jj];
    }
    __syncthreads();

    if (!half) {
#pragma unroll
        for (int jj = 0; jj < 4; ++jj) sacc[jj] += red[lt][jj];
        // partial layout: [s*P1+p][ i*1024 + lt*4 + jj ] Sxx, [16384 + lt*4 + jj] Sx
        float* dst = part + (size_t)(s * P1 + p) * PART_STRIDE;
#pragma unroll
        for (int i = 0; i < GD; ++i)
            *(float4*)&dst[i * D_FEAT + lt * 4] =
                make_float4(acc[i][0], acc[i][1], acc[i][2], acc[i][3]);
        *(float4*)&dst[SXX_FLOATS + lt * 4] =
            make_float4(sacc[0], sacc[1], sacc[2], sacc[3]);
    }
}

// ---------------- Pass 1b: reduce partials, stage 1 (P1 -> PSPLIT) ----------------
__global__ __launch_bounds__(256) void k_reduce1(const float* __restrict__ part,
                                                 float* __restrict__ red) {
    const int f = blockIdx.x * 256 + threadIdx.x;
    if (f >= ENT) return;
    const int s = f / PART_STRIDE, ff = f % PART_STRIDE;
    constexpr int PER = P1 / PSPLIT;                 // 32
    const float* src = part + ((size_t)s * P1 + blockIdx.y * PER) * PART_STRIDE + ff;
    float sum = 0.0f;
#pragma unroll 8
    for (int p = 0; p < PER; ++p) sum += src[(size_t)p * PART_STRIDE];
    red[(size_t)blockIdx.y * ENT + f] = sum;
}

// ---------------- Pass 1c: reduce stage 2 (PSPLIT -> 1) + scatter into ws ----------------
__global__ __launch_bounds__(256) void k_reduce2(const float* __restrict__ red,
                                                 float* __restrict__ ws) {
    const int f = blockIdx.x * 256 + threadIdx.x;
    if (f >= ENT) return;
    float sum = 0.0f;
#pragma unroll
    for (int pp = 0; pp < PSPLIT; ++pp) sum += red[(size_t)pp * ENT + f];
    const int s = f / PART_STRIDE, rest = f % PART_STRIDE;
    if (rest < SXX_FLOATS) {
        // rest = i*1024 + g*16 + j
        const int i = rest >> 10;
        const int g = (rest & 1023) >> 4;
        const int j = rest & 15;
        ws[SXX_OFF + (size_t)((s * NGROUP + g) * GD + i) * GD + j] = sum;
    } else {
        ws[SX_OFF + s * D_FEAT + (rest - SXX_FLOATS)] = sum;
    }
}

// ---------------- Pass 2: W = cov^{-1/2} via Newton-Schulz ----------------
// one block per (s,g); thread = (i = tid>>4, j = tid&15) entry of 16x16.
__global__ __launch_bounds__(256) void k_invsqrt(float* __restrict__ ws) {
    __shared__ float Ym[GD][GD];
    __shared__ float Zm[GD][GD];
    __shared__ float Tm[GD][GD];
    const int bx = blockIdx.x;
    const int s = bx / NGROUP, g = bx % NGROUP;
    const int tid = threadIdx.x;
    const int i = tid >> 4, j = tid & 15;
    const float invB = 1.0f / (float)NB;

    const float sxx = ws[SXX_OFF + (size_t)((s * NGROUP + g) * GD + i) * GD + j];
    const float mui = ws[SX_OFF + s * D_FEAT + g * GD + i] * invB;
    const float muj = ws[SX_OFF + s * D_FEAT + g * GD + j] * invB;
    const float a = sxx * invB - mui * muj;   // cov entry

    Ym[i][j] = a;
    __syncthreads();
    float tr = 0.0f;
#pragma unroll
    for (int k = 0; k < GD; ++k) tr += Ym[k][k];
    const float sc = tr * (1.0f / (float)GD);   // ~1.0 for N(0,1) data
    const float inv_sc = 1.0f / sc;
    __syncthreads();                            // all trace reads done
    Ym[i][j] = a * inv_sc;                      // normalized A, eig in ~[0.9,1.1]
    Zm[i][j] = (i == j) ? 1.0f : 0.0f;
    __syncthreads();

    float zn = (i == j) ? 1.0f : 0.0f;
    for (int it = 0; it < 6; ++it) {
        float t = 0.0f;
#pragma unroll
        for (int k = 0; k < GD; ++k) t += Zm[i][k] * Ym[k][j];
        t = ((i == j) ? 1.5f : 0.0f) - 0.5f * t;
        Tm[i][j] = t;
        __syncthreads();
        float yn = 0.0f;
        zn = 0.0f;
#pragma unroll
        for (int k = 0; k < GD; ++k) {
            yn += Ym[i][k] * Tm[k][j];
            zn += Tm[i][k] * Zm[k][j];
        }
        __syncthreads();
        Ym[i][j] = yn;
        Zm[i][j] = zn;
        __syncthreads();
    }
    // W = Z * sc^{-1/2}
    ws[W_OFF + (size_t)((s * NGROUP + g) * GD + i) * GD + j] = zn * rsqrtf(sc);
}

// ---------------- Pass 3: y = (x_gathered - mu) @ W, scattered back ----------------
// block: 256 threads; thread = (g = tid>>2, q = tid&3) owns W[:, q*4..q*4+3] in regs;
// gathers its quad from LDS, rebuilds v[16] via DPP, scatters u[4] to bout.
// (Exact R5/R8 kernel — proven.)
__global__ __launch_bounds__(256, 3) void k_apply(const float* __restrict__ x,
                                                  const int* __restrict__ perms,
                                                  const float* __restrict__ ws,
                                                  float* __restrict__ out) {
    __shared__ float bin[2][C3][D_FEAT];             // 32 KB double-buffered input
    __shared__ float bout[C3][D_FEAT];               // 16 KB output staging
    const int s   = blockIdx.y;
    const int rb  = blockIdx.x;
    const int tid = threadIdx.x;
    const int g   = tid >> 2;
    const int q   = tid & 3;
    const float invB = 1.0f / (float)NB;

    int pcolq[4];
#pragma unroll
    for (int jj = 0; jj < 4; ++jj) pcolq[jj] = perms[s * D_FEAT + tid * 4 + jj];

    // W columns for this thread: w[e][ii] = W[s,g][e][q*4+ii]
    const float* Wp = ws + W_OFF + (size_t)(s * NGROUP + g) * GD * GD;
    float w[GD][4];
#pragma unroll
    for (int e = 0; e < GD; ++e) {
        float4 t4 = *(const float4*)&Wp[e * GD + q * 4];
        w[e][0] = t4.x; w[e][1] = t4.y; w[e][2] = t4.z; w[e][3] = t4.w;
    }
    // bias[ii] = sum_e mu[e] * w[e][ii]  (fold centering into the GEMV)
    float bias[4] = {0.0f, 0.0f, 0.0f, 0.0f};
#pragma unroll
    for (int e = 0; e < GD; ++e) {
        const float mu = ws[SX_OFF + s * D_FEAT + g * GD + e] * invB;
#pragma unroll
        for (int ii = 0; ii < 4; ++ii) bias[ii] += mu * w[e][ii];
    }

    const float* xbase = x + (size_t)(s * NB + rb * RPB3) * D_FEAT;
    float* obase = out + (size_t)(s * NB + rb * RPB3) * D_FEAT;
    constexpr int NCH = RPB3 / C3;                   // 8 chunks

    float4 rr[C3];
#pragma unroll
    for (int t = 0; t < C3; ++t)
        rr[t] = *(const float4*)&xbase[(size_t)t * D_FEAT + tid * 4];

    for (int k = 0; k < NCH; ++k) {
#pragma unroll
        for (int t = 0; t < C3; ++t)
            *(float4*)&bin[k & 1][t][tid * 4] = rr[t];
        __syncthreads();                             // bin[k&1] visible; bout(k-1) stores done
        if (k + 1 < NCH) {                           // prefetch under compute
            const float* nx = xbase + (size_t)(k + 1) * C3 * D_FEAT;
#pragma unroll
            for (int t = 0; t < C3; ++t)
                rr[t] = *(const float4*)&nx[(size_t)t * D_FEAT + tid * 4];
        }
        const float (*cb)[D_FEAT] = bin[k & 1];
#pragma unroll
        for (int r = 0; r < C3; ++r) {
            float vq[4];
#pragma unroll
            for (int jj = 0; jj < 4; ++jj) vq[jj] = cb[r][pcolq[jj]];
            float v[GD];
#pragma unroll
            for (int jj = 0; jj < 4; ++jj) {
                v[0  + jj] = qbc<0>(vq[jj]);
                v[4  + jj] = qbc<1>(vq[jj]);
                v[8  + jj] = qbc<2>(vq[jj]);
                v[12 + jj] = qbc<3>(vq[jj]);
            }
            float u[4] = {-bias[0], -bias[1], -bias[2], -bias[3]};
#pragma unroll
            for (int e = 0; e < GD; ++e)
#pragma unroll
                for (int ii = 0; ii < 4; ++ii) u[ii] = fmaf(v[e], w[e][ii], u[ii]);
#pragma unroll
            for (int ii = 0; ii < 4; ++ii) bout[r][pcolq[ii]] = u[ii];
        }
        __syncthreads();                             // bout complete
        float* ob = obase + (size_t)k * C3 * D_FEAT;
#pragma unroll
        for (int t = 0; t < C3; ++t)
            *(float4*)&ob[(size_t)t * D_FEAT + tid * 4] =
                *(const float4*)&bout[t][tid * 4];
    }
}

extern "C" void kernel_launch(void* const* d_in, const int* in_sizes, int n_in,
                              void* d_out, int out_size, void* d_ws, size_t ws_size,
                              hipStream_t stream) {
    const float* x     = (const float*)d_in[0];
    const int*   perms = (const int*)d_in[1];
    float* out = (float*)d_out;
    float* ws  = (float*)d_ws;

    // Partials (3*256*17408 floats = 53.5 MB) live in d_out: it is 100 MB and
    // k_apply fully overwrites every element afterwards. ws only needs 2.1 MB.
    float* part = out;

    dim3 g1(P1, NVIEW);                              // 768 blocks of 512 thr
    k_stats_gather<<<g1, 512, 0, stream>>>(x, perms, part);

    dim3 gr1((ENT + 255) / 256, PSPLIT);             // (204, 8)
    k_reduce1<<<gr1, 256, 0, stream>>>(part, ws + RED_OFF);
    k_reduce2<<<(ENT + 255) / 256, 256, 0, stream>>>(ws + RED_OFF, ws);

    k_invsqrt<<<NVIEW * NGROUP, 256, 0, stream>>>(ws);

    dim3 g3(NB / RPB3, NVIEW);                       // 768 blocks = 3/CU
    k_apply<<<g3, 256, 0, stream>>>(x, perms, ws, out);
}

// Round 10
// 104.599 us; speedup vs baseline: 1.7301x; 1.7301x over previous
//
#include <hip/hip_runtime.h>
#include <stdint.h>

// ShuffledGroupWhitening on MI355X.
// x: [3*8192, 1024] f32, perms: [3,1024] i32.
// Per (view s, group g): gather 16 permuted cols, center over batch,
// whiten with cov^{-1/2} (Newton-Schulz), scatter back (same col set).
//
// R9 -> R10: R9's launch_bounds(512,6) spilled acc[16][4] (VGPR cap 40) ->
// scratch traffic, 148 us. Reverted to R8's exact hot loop (48 VGPR, no
// spill). TLP now comes from the GRID: P1=512 (1536 blocks = 6/CU = 24
// waves/CU), 16 rows/block. Partials packed to bf16 (RNE) so 512 partials
// fit in d_out (53.5 MB) -- also halves reduce traffic. Precision: bf16
// partial error ~5e-5 on cov, ~1e-4 on y vs 0.109 threshold.

constexpr int D_FEAT  = 1024;
constexpr int NGROUP  = 64;
constexpr int GD      = 16;     // group dim
constexpr int NB      = 8192;   // rows per view
constexpr int NVIEW   = 3;

constexpr int P1      = 512;    // stats blocks per view (1536 total = 6/CU)
constexpr int RPP1    = NB / P1;        // 16 rows per stats block
constexpr int RPB3    = 32;     // rows per apply block
constexpr int C3      = 4;      // chunk rows (apply)
constexpr int PSPLIT  = 16;     // reduce split factor
constexpr int PER     = P1 / PSPLIT;    // 32 partials per reduce1 block

constexpr int SXX_FLOATS  = NGROUP * GD * GD;        // 16384 per view
constexpr int PART_STRIDE = SXX_FLOATS + D_FEAT;     // 17408 entries per partial
constexpr int PSTRIDE_U32 = PART_STRIDE / 2;         // 8704 dwords (bf16-packed)
constexpr int ENT         = NVIEW * PART_STRIDE;     // 52224 stat entries
constexpr int ENT_DW      = NVIEW * PSTRIDE_U32;     // 26112 packed dwords

// ws layout (floats) — partials live in d_out, NOT here
constexpr int SXX_OFF = 0;                           // [3][64][16][16]
constexpr int SX_OFF  = NVIEW * SXX_FLOATS;          // 49152: [3][1024]
constexpr int W_OFF   = SX_OFF + NVIEW * D_FEAT;     // 52224: [3][64][16][16]
constexpr int RED_OFF = W_OFF + NVIEW * SXX_FLOATS;  // 101376: [16][52224]
// total ws use = RED_OFF + PSPLIT*ENT = 936960 floats ~ 3.75 MB

// quad broadcast: every lane gets lane ((lane&~3)+B)'s value. Pure VALU DPP.
template <int B>
__device__ __forceinline__ float qbc(float x) {
    return __int_as_float(__builtin_amdgcn_mov_dpp(
        __float_as_int(x), B * 0x55 /*quad_perm[B,B,B,B]*/, 0xF, 0xF, true));
}

// pack two floats to bf16x2 (round-to-nearest-even), a in low half
__device__ __forceinline__ uint32_t pkbf2(float a, float b) {
    uint32_t ua = __float_as_uint(a), ub = __float_as_uint(b);
    ua += 0x7FFFu + ((ua >> 16) & 1u);
    ub += 0x7FFFu + ((ub >> 16) & 1u);
    return (ua >> 16) | (ub & 0xFFFF0000u);
}

// ---------------- Pass 1a: per-block partial Sxx and Sx (bf16-packed) -------------
// 256 threads; thread = (g = tid>>2, q = tid&3) gathers its own quad directly
// from global (block reads whole rows -> L2/L3 absorb line overlap), DPP
// rebuilds v[16], accumulates acc[i][jj] = sum v[i]*vq[jj]. R8 hot loop.
__global__ __launch_bounds__(256, 3) void k_stats_gather(const float* __restrict__ x,
                                                         const int* __restrict__ perms,
                                                         uint32_t* __restrict__ part) {
    const int s   = blockIdx.y;
    const int p   = blockIdx.x;
    const int tid = threadIdx.x;

    // this thread's 4 permuted column indices (coalesced load)
    int pcolq[4];
#pragma unroll
    for (int jj = 0; jj < 4; ++jj) pcolq[jj] = perms[s * D_FEAT + tid * 4 + jj];

    float acc[GD][4];
#pragma unroll
    for (int i = 0; i < GD; ++i)
#pragma unroll
        for (int jj = 0; jj < 4; ++jj) acc[i][jj] = 0.0f;
    float sacc[4] = {0.0f, 0.0f, 0.0f, 0.0f};

    const float* xbase = x + (size_t)(s * NB + p * RPP1) * D_FEAT;

// accumulate one row given its 4 gathered quad values
#define ROW_ACC(Q0, Q1, Q2, Q3)                                                \
    {                                                                          \
        float vq_[4] = {Q0, Q1, Q2, Q3};                                       \
        float v_[GD];                                                          \
        _Pragma("unroll")                                                      \
        for (int jj = 0; jj < 4; ++jj) {                                       \
            v_[0  + jj] = qbc<0>(vq_[jj]);                                     \
            v_[4  + jj] = qbc<1>(vq_[jj]);                                     \
            v_[8  + jj] = qbc<2>(vq_[jj]);                                     \
            v_[12 + jj] = qbc<3>(vq_[jj]);                                     \
        }                                                                      \
        _Pragma("unroll")                                                      \
        for (int jj = 0; jj < 4; ++jj) sacc[jj] += vq_[jj];                    \
        _Pragma("unroll")                                                      \
        for (int i = 0; i < GD; ++i)                                           \
            _Pragma("unroll")                                                  \
            for (int jj = 0; jj < 4; ++jj)                                     \
                acc[i][jj] = fmaf(v_[i], vq_[jj], acc[i][jj]);                 \
    }

    // 4 rows per iteration: 16 independent dword gathers in flight per wave.
    for (int r = 0; r < RPP1; r += 4) {
        const float* r0 = xbase + (size_t)r * D_FEAT;
        const float* r1 = r0 + D_FEAT;
        const float* r2 = r1 + D_FEAT;
        const float* r3 = r2 + D_FEAT;
        const float a0 = r0[pcolq[0]], a1 = r0[pcolq[1]],
                    a2 = r0[pcolq[2]], a3 = r0[pcolq[3]];
        const float b0 = r1[pcolq[0]], b1 = r1[pcolq[1]],
                    b2 = r1[pcolq[2]], b3 = r1[pcolq[3]];
        const float c0 = r2[pcolq[0]], c1 = r2[pcolq[1]],
                    c2 = r2[pcolq[2]], c3 = r2[pcolq[3]];
        const float d0 = r3[pcolq[0]], d1 = r3[pcolq[1]],
                    d2 = r3[pcolq[2]], d3 = r3[pcolq[3]];
        ROW_ACC(a0, a1, a2, a3)
        ROW_ACC(b0, b1, b2, b3)
        ROW_ACC(c0, c1, c2, c3)
        ROW_ACC(d0, d1, d2, d3)
    }
#undef ROW_ACC

    // bf16-packed partial: dword layout [i*512 + tid*2 + h] for Sxx,
    // [8192 + tid*2 + h] for Sx; entry (i*1024 + tid*4 + jj) <-> dword
    // (i*512 + tid*2 + (jj>>1)), half jj&1.
    uint32_t* dst = part + (size_t)(s * P1 + p) * PSTRIDE_U32;
#pragma unroll
    for (int i = 0; i < GD; ++i) {
        dst[i * 512 + tid * 2 + 0] = pkbf2(acc[i][0], acc[i][1]);
        dst[i * 512 + tid * 2 + 1] = pkbf2(acc[i][2], acc[i][3]);
    }
    dst[8192 + tid * 2 + 0] = pkbf2(sacc[0], sacc[1]);
    dst[8192 + tid * 2 + 1] = pkbf2(sacc[2], sacc[3]);
}

// ---------------- Pass 1b: reduce bf16 partials, stage 1 (P1 -> PSPLIT) -----------
// one thread per packed dword (2 entries); coalesced reads per p-iter.
__global__ __launch_bounds__(256) void k_reduce1(const uint32_t* __restrict__ part,
                                                 float* __restrict__ red) {
    const int fd = blockIdx.x * 256 + threadIdx.x;
    if (fd >= ENT_DW) return;
    const int s = fd / PSTRIDE_U32, ffd = fd % PSTRIDE_U32;
    const uint32_t* src =
        part + ((size_t)s * P1 + blockIdx.y * PER) * PSTRIDE_U32 + ffd;
    float s0 = 0.0f, s1 = 0.0f;
#pragma unroll 8
    for (int p = 0; p < PER; ++p) {
        const uint32_t u = src[(size_t)p * PSTRIDE_U32];
        s0 += __uint_as_float(u << 16);
        s1 += __uint_as_float(u & 0xFFFF0000u);
    }
    float* r = red + (size_t)blockIdx.y * ENT + s * PART_STRIDE + ffd * 2;
    r[0] = s0;
    r[1] = s1;
}

// ---------------- Pass 1c: reduce stage 2 (PSPLIT -> 1) + scatter into ws ----------
__global__ __launch_bounds__(256) void k_reduce2(const float* __restrict__ red,
                                                 float* __restrict__ ws) {
    const int f = blockIdx.x * 256 + threadIdx.x;
    if (f >= ENT) return;
    float sum = 0.0f;
#pragma unroll
    for (int pp = 0; pp < PSPLIT; ++pp) sum += red[(size_t)pp * ENT + f];
    const int s = f / PART_STRIDE, rest = f % PART_STRIDE;
    if (rest < SXX_FLOATS) {
        // rest = i*1024 + g*16 + j
        const int i = rest >> 10;
        const int g = (rest & 1023) >> 4;
        const int j = rest & 15;
        ws[SXX_OFF + (size_t)((s * NGROUP + g) * GD + i) * GD + j] = sum;
    } else {
        ws[SX_OFF + s * D_FEAT + (rest - SXX_FLOATS)] = sum;
    }
}

// ---------------- Pass 2: W = cov^{-1/2} via Newton-Schulz ----------------
// one block per (s,g); thread = (i = tid>>4, j = tid&15) entry of 16x16.
__global__ __launch_bounds__(256) void k_invsqrt(float* __restrict__ ws) {
    __shared__ float Ym[GD][GD];
    __shared__ float Zm[GD][GD];
    __shared__ float Tm[GD][GD];
    const int bx = blockIdx.x;
    const int s = bx / NGROUP, g = bx % NGROUP;
    const int tid = threadIdx.x;
    const int i = tid >> 4, j = tid & 15;
    const float invB = 1.0f / (float)NB;

    const float sxx = ws[SXX_OFF + (size_t)((s * NGROUP + g) * GD + i) * GD + j];
    const float mui = ws[SX_OFF + s * D_FEAT + g * GD + i] * invB;
    const float muj = ws[SX_OFF + s * D_FEAT + g * GD + j] * invB;
    const float a = sxx * invB - mui * muj;   // cov entry

    Ym[i][j] = a;
    __syncthreads();
    float tr = 0.0f;
#pragma unroll
    for (int k = 0; k < GD; ++k) tr += Ym[k][k];
    const float sc = tr * (1.0f / (float)GD);   // ~1.0 for N(0,1) data
    const float inv_sc = 1.0f / sc;
    __syncthreads();                            // all trace reads done
    Ym[i][j] = a * inv_sc;                      // normalized A, eig in ~[0.9,1.1]
    Zm[i][j] = (i == j) ? 1.0f : 0.0f;
    __syncthreads();

    float zn = (i == j) ? 1.0f : 0.0f;
    for (int it = 0; it < 6; ++it) {
        float t = 0.0f;
#pragma unroll
        for (int k = 0; k < GD; ++k) t += Zm[i][k] * Ym[k][j];
        t = ((i == j) ? 1.5f : 0.0f) - 0.5f * t;
        Tm[i][j] = t;
        __syncthreads();
        float yn = 0.0f;
        zn = 0.0f;
#pragma unroll
        for (int k = 0; k < GD; ++k) {
            yn += Ym[i][k] * Tm[k][j];
            zn += Tm[i][k] * Zm[k][j];
        }
        __syncthreads();
        Ym[i][j] = yn;
        Zm[i][j] = zn;
        __syncthreads();
    }
    // W = Z * sc^{-1/2}
    ws[W_OFF + (size_t)((s * NGROUP + g) * GD + i) * GD + j] = zn * rsqrtf(sc);
}

// ---------------- Pass 3: y = (x_gathered - mu) @ W, scattered back ----------------
// block: 256 threads; thread = (g = tid>>2, q = tid&3) owns W[:, q*4..q*4+3] in regs;
// gathers its quad from LDS, rebuilds v[16] via DPP, scatters u[4] to bout.
// (Exact R5/R8 kernel — proven.)
__global__ __launch_bounds__(256, 3) void k_apply(const float* __restrict__ x,
                                                  const int* __restrict__ perms,
                                                  const float* __restrict__ ws,
                                                  float* __restrict__ out) {
    __shared__ float bin[2][C3][D_FEAT];             // 32 KB double-buffered input
    __shared__ float bout[C3][D_FEAT];               // 16 KB output staging
    const int s   = blockIdx.y;
    const int rb  = blockIdx.x;
    const int tid = threadIdx.x;
    const int g   = tid >> 2;
    const int q   = tid & 3;
    const float invB = 1.0f / (float)NB;

    int pcolq[4];
#pragma unroll
    for (int jj = 0; jj < 4; ++jj) pcolq[jj] = perms[s * D_FEAT + tid * 4 + jj];

    // W columns for this thread: w[e][ii] = W[s,g][e][q*4+ii]
    const float* Wp = ws + W_OFF + (size_t)(s * NGROUP + g) * GD * GD;
    float w[GD][4];
#pragma unroll
    for (int e = 0; e < GD; ++e) {
        float4 t4 = *(const float4*)&Wp[e * GD + q * 4];
        w[e][0] = t4.x; w[e][1] = t4.y; w[e][2] = t4.z; w[e][3] = t4.w;
    }
    // bias[ii] = sum_e mu[e] * w[e][ii]  (fold centering into the GEMV)
    float bias[4] = {0.0f, 0.0f, 0.0f, 0.0f};
#pragma unroll
    for (int e = 0; e < GD; ++e) {
        const float mu = ws[SX_OFF + s * D_FEAT + g * GD + e] * invB;
#pragma unroll
        for (int ii = 0; ii < 4; ++ii) bias[ii] += mu * w[e][ii];
    }

    const float* xbase = x + (size_t)(s * NB + rb * RPB3) * D_FEAT;
    float* obase = out + (size_t)(s * NB + rb * RPB3) * D_FEAT;
    constexpr int NCH = RPB3 / C3;                   // 8 chunks

    float4 rr[C3];
#pragma unroll
    for (int t = 0; t < C3; ++t)
        rr[t] = *(const float4*)&xbase[(size_t)t * D_FEAT + tid * 4];

    for (int k = 0; k < NCH; ++k) {
#pragma unroll
        for (int t = 0; t < C3; ++t)
            *(float4*)&bin[k & 1][t][tid * 4] = rr[t];
        __syncthreads();                             // bin[k&1] visible; bout(k-1) stores done
        if (k + 1 < NCH) {                           // prefetch under compute
            const float* nx = xbase + (size_t)(k + 1) * C3 * D_FEAT;
#pragma unroll
            for (int t = 0; t < C3; ++t)
                rr[t] = *(const float4*)&nx[(size_t)t * D_FEAT + tid * 4];
        }
        const float (*cb)[D_FEAT] = bin[k & 1];
#pragma unroll
        for (int r = 0; r < C3; ++r) {
            float vq[4];
#pragma unroll
            for (int jj = 0; jj < 4; ++jj) vq[jj] = cb[r][pcolq[jj]];
            float v[GD];
#pragma unroll
            for (int jj = 0; jj < 4; ++jj) {
                v[0  + jj] = qbc<0>(vq[jj]);
                v[4  + jj] = qbc<1>(vq[jj]);
                v[8  + jj] = qbc<2>(vq[jj]);
                v[12 + jj] = qbc<3>(vq[jj]);
            }
            float u[4] = {-bias[0], -bias[1], -bias[2], -bias[3]};
#pragma unroll
            for (int e = 0; e < GD; ++e)
#pragma unroll
                for (int ii = 0; ii < 4; ++ii) u[ii] = fmaf(v[e], w[e][ii], u[ii]);
#pragma unroll
            for (int ii = 0; ii < 4; ++ii) bout[r][pcolq[ii]] = u[ii];
        }
        __syncthreads();                             // bout complete
        float* ob = obase + (size_t)k * C3 * D_FEAT;
#pragma unroll
        for (int t = 0; t < C3; ++t)
            *(float4*)&ob[(size_t)t * D_FEAT + tid * 4] =
                *(const float4*)&bout[t][tid * 4];
    }
}

extern "C" void kernel_launch(void* const* d_in, const int* in_sizes, int n_in,
                              void* d_out, int out_size, void* d_ws, size_t ws_size,
                              hipStream_t stream) {
    const float* x     = (const float*)d_in[0];
    const int*   perms = (const int*)d_in[1];
    float* out = (float*)d_out;
    float* ws  = (float*)d_ws;

    // bf16-packed partials (1536 * 8704 dwords = 53.5 MB) live in d_out:
    // it is 100.7 MB and k_apply fully overwrites every element afterwards.
    uint32_t* part = (uint32_t*)out;

    dim3 g1(P1, NVIEW);                              // 1536 blocks = 6/CU
    k_stats_gather<<<g1, 256, 0, stream>>>(x, perms, part);

    dim3 gr1((ENT_DW + 255) / 256, PSPLIT);          // (102, 16)
    k_reduce1<<<gr1, 256, 0, stream>>>(part, ws + RED_OFF);
    k_reduce2<<<(ENT + 255) / 256, 256, 0, stream>>>(ws + RED_OFF, ws);

    k_invsqrt<<<NVIEW * NGROUP, 256, 0, stream>>>(ws);

    dim3 g3(NB / RPB3, NVIEW);                       // 768 blocks = 3/CU
    k_apply<<<g3, 256, 0, stream>>>(x, perms, ws, out);
}

// Round 11
// 96.812 us; speedup vs baseline: 1.8692x; 1.0804x over previous
//
#include <hip/hip_runtime.h>
#include <stdint.h>

// ShuffledGroupWhitening on MI355X.
// x: [3*8192, 1024] f32, perms: [3,1024] i32.
// Per (view s, group g): gather 16 permuted cols, center over batch,
// whiten with cov^{-1/2} (Newton-Schulz), scatter back (same col set).
//
// R10 -> R11: stats is pinned at ~58-64 us across 4 structures (LDS-staged,
// LDS-pipelined, direct-gather, 2x TLP) -> scattered-access floor (~2 cyc per
// unique (row,col) touch; 25.2M touches). Harvest the tail instead:
// P1=256 + bf16 partials (26.7 MB, halves reduce1 traffic), and fuse the
// stage-2 reduce into invsqrt (one launch + ws round-trip deleted).
// Stats hot loop and apply are byte-identical to the proven R8/R10 code.

constexpr int D_FEAT  = 1024;
constexpr int NGROUP  = 64;
constexpr int GD      = 16;     // group dim
constexpr int NB      = 8192;   // rows per view
constexpr int NVIEW   = 3;

constexpr int P1      = 256;    // stats blocks per view (768 total = 3/CU)
constexpr int RPP1    = NB / P1;        // 32 rows per stats block
constexpr int RPB3    = 32;     // rows per apply block
constexpr int C3      = 4;      // chunk rows (apply)
constexpr int PSPLIT  = 8;      // reduce split factor
constexpr int PER     = P1 / PSPLIT;    // 32 partials per reduce1 block

constexpr int SXX_FLOATS  = NGROUP * GD * GD;        // 16384 per view
constexpr int PART_STRIDE = SXX_FLOATS + D_FEAT;     // 17408 entries per partial
constexpr int PSTRIDE_U32 = PART_STRIDE / 2;         // 8704 dwords (bf16-packed)
constexpr int ENT         = NVIEW * PART_STRIDE;     // 52224 stat entries
constexpr int ENT_DW      = NVIEW * PSTRIDE_U32;     // 26112 packed dwords

// ws layout (floats) — partials live in d_out, NOT here
constexpr int SX_OFF  = 0;                           // [3][1024] raw col sums
constexpr int W_OFF   = SX_OFF + NVIEW * D_FEAT;     // 3072: [3][64][16][16]
constexpr int RED_OFF = W_OFF + NVIEW * SXX_FLOATS;  // 52224: [8][52224] f32
// total ws use = RED_OFF + PSPLIT*ENT = 470016 floats ~ 1.9 MB

// quad broadcast: every lane gets lane ((lane&~3)+B)'s value. Pure VALU DPP.
template <int B>
__device__ __forceinline__ float qbc(float x) {
    return __int_as_float(__builtin_amdgcn_mov_dpp(
        __float_as_int(x), B * 0x55 /*quad_perm[B,B,B,B]*/, 0xF, 0xF, true));
}

// pack two floats to bf16x2 (round-to-nearest-even), a in low half
__device__ __forceinline__ uint32_t pkbf2(float a, float b) {
    uint32_t ua = __float_as_uint(a), ub = __float_as_uint(b);
    ua += 0x7FFFu + ((ua >> 16) & 1u);
    ub += 0x7FFFu + ((ub >> 16) & 1u);
    return (ua >> 16) | (ub & 0xFFFF0000u);
}

// ---------------- Pass 1a: per-block partial Sxx and Sx (bf16-packed) -------------
// 256 threads; thread = (g = tid>>2, q = tid&3) gathers its own quad directly
// from global (block reads whole rows -> L2/L3 absorb line overlap), DPP
// rebuilds v[16], accumulates acc[i][jj] = sum v[i]*vq[jj]. R8 hot loop.
__global__ __launch_bounds__(256, 3) void k_stats_gather(const float* __restrict__ x,
                                                         const int* __restrict__ perms,
                                                         uint32_t* __restrict__ part) {
    const int s   = blockIdx.y;
    const int p   = blockIdx.x;
    const int tid = threadIdx.x;

    // this thread's 4 permuted column indices (coalesced load)
    int pcolq[4];
#pragma unroll
    for (int jj = 0; jj < 4; ++jj) pcolq[jj] = perms[s * D_FEAT + tid * 4 + jj];

    float acc[GD][4];
#pragma unroll
    for (int i = 0; i < GD; ++i)
#pragma unroll
        for (int jj = 0; jj < 4; ++jj) acc[i][jj] = 0.0f;
    float sacc[4] = {0.0f, 0.0f, 0.0f, 0.0f};

    const float* xbase = x + (size_t)(s * NB + p * RPP1) * D_FEAT;

// accumulate one row given its 4 gathered quad values
#define ROW_ACC(Q0, Q1, Q2, Q3)                                                \
    {                                                                          \
        float vq_[4] = {Q0, Q1, Q2, Q3};                                       \
        float v_[GD];                                                          \
        _Pragma("unroll")                                                      \
        for (int jj = 0; jj < 4; ++jj) {                                       \
            v_[0  + jj] = qbc<0>(vq_[jj]);                                     \
            v_[4  + jj] = qbc<1>(vq_[jj]);                                     \
            v_[8  + jj] = qbc<2>(vq_[jj]);                                     \
            v_[12 + jj] = qbc<3>(vq_[jj]);                                     \
        }                                                                      \
        _Pragma("unroll")                                                      \
        for (int jj = 0; jj < 4; ++jj) sacc[jj] += vq_[jj];                    \
        _Pragma("unroll")                                                      \
        for (int i = 0; i < GD; ++i)                                           \
            _Pragma("unroll")                                                  \
            for (int jj = 0; jj < 4; ++jj)                                     \
                acc[i][jj] = fmaf(v_[i], vq_[jj], acc[i][jj]);                 \
    }

    // 4 rows per iteration: 16 independent dword gathers in flight per wave.
    for (int r = 0; r < RPP1; r += 4) {
        const float* r0 = xbase + (size_t)r * D_FEAT;
        const float* r1 = r0 + D_FEAT;
        const float* r2 = r1 + D_FEAT;
        const float* r3 = r2 + D_FEAT;
        const float a0 = r0[pcolq[0]], a1 = r0[pcolq[1]],
                    a2 = r0[pcolq[2]], a3 = r0[pcolq[3]];
        const float b0 = r1[pcolq[0]], b1 = r1[pcolq[1]],
                    b2 = r1[pcolq[2]], b3 = r1[pcolq[3]];
        const float c0 = r2[pcolq[0]], c1 = r2[pcolq[1]],
                    c2 = r2[pcolq[2]], c3 = r2[pcolq[3]];
        const float d0 = r3[pcolq[0]], d1 = r3[pcolq[1]],
                    d2 = r3[pcolq[2]], d3 = r3[pcolq[3]];
        ROW_ACC(a0, a1, a2, a3)
        ROW_ACC(b0, b1, b2, b3)
        ROW_ACC(c0, c1, c2, c3)
        ROW_ACC(d0, d1, d2, d3)
    }
#undef ROW_ACC

    // bf16-packed partial: dword layout [i*512 + tid*2 + h] for Sxx,
    // [8192 + tid*2 + h] for Sx; entry (i*1024 + tid*4 + jj) <-> dword
    // (i*512 + tid*2 + (jj>>1)), half jj&1.
    uint32_t* dst = part + (size_t)(s * P1 + p) * PSTRIDE_U32;
#pragma unroll
    for (int i = 0; i < GD; ++i) {
        dst[i * 512 + tid * 2 + 0] = pkbf2(acc[i][0], acc[i][1]);
        dst[i * 512 + tid * 2 + 1] = pkbf2(acc[i][2], acc[i][3]);
    }
    dst[8192 + tid * 2 + 0] = pkbf2(sacc[0], sacc[1]);
    dst[8192 + tid * 2 + 1] = pkbf2(sacc[2], sacc[3]);
}

// ---------------- Pass 1b: reduce bf16 partials, stage 1 (P1 -> PSPLIT) -----------
// one thread per packed dword (2 entries); coalesced reads per p-iter.
// red[pp][f] holds f32 sums at natural entry index f (i*1024 + c' for Sxx,
// 16384 + c' for Sx), per view offset s*PART_STRIDE.
__global__ __launch_bounds__(256) void k_reduce1(const uint32_t* __restrict__ part,
                                                 float* __restrict__ red) {
    const int fd = blockIdx.x * 256 + threadIdx.x;
    if (fd >= ENT_DW) return;
    const int s = fd / PSTRIDE_U32, ffd = fd % PSTRIDE_U32;
    const uint32_t* src =
        part + ((size_t)s * P1 + blockIdx.y * PER) * PSTRIDE_U32 + ffd;
    float s0 = 0.0f, s1 = 0.0f;
#pragma unroll 8
    for (int p = 0; p < PER; ++p) {
        const uint32_t u = src[(size_t)p * PSTRIDE_U32];
        s0 += __uint_as_float(u << 16);
        s1 += __uint_as_float(u & 0xFFFF0000u);
    }
    float* r = red + (size_t)blockIdx.y * ENT + s * PART_STRIDE + ffd * 2;
    r[0] = s0;
    r[1] = s1;
}

// ---------------- Pass 2: fused final-reduce + W = cov^{-1/2} ----------------
// one block per (s,g); thread (i = tid>>4, j = tid&15) sums its Sxx entry over
// the 8 red slices, threads 0..15 produce mu and store raw Sx to ws for apply,
// then Newton-Schulz in LDS.
__global__ __launch_bounds__(256) void k_invsqrt(const float* __restrict__ red,
                                                 float* __restrict__ ws) {
    __shared__ float Ym[GD][GD];
    __shared__ float Zm[GD][GD];
    __shared__ float Tm[GD][GD];
    __shared__ float Mu[GD];
    const int bx = blockIdx.x;
    const int s = bx >> 6, g = bx & 63;
    const int tid = threadIdx.x;
    const int i = tid >> 4, j = tid & 15;
    const float invB = 1.0f / (float)NB;

    // final 8-way reduction for this thread's Sxx entry
    const int f_sxx = s * PART_STRIDE + i * D_FEAT + g * GD + j;
    float sxx = 0.0f;
#pragma unroll
    for (int pp = 0; pp < PSPLIT; ++pp) sxx += red[(size_t)pp * ENT + f_sxx];

    // threads 0..15: final Sx sum -> mu (LDS) + raw Sx to ws (apply reads it)
    if (tid < GD) {
        const int f_sx = s * PART_STRIDE + SXX_FLOATS + g * GD + tid;
        float sx = 0.0f;
#pragma unroll
        for (int pp = 0; pp < PSPLIT; ++pp) sx += red[(size_t)pp * ENT + f_sx];
        ws[SX_OFF + s * D_FEAT + g * GD + tid] = sx;
        Mu[tid] = sx * invB;
    }
    __syncthreads();
    const float a = sxx * invB - Mu[i] * Mu[j];   // cov entry

    Ym[i][j] = a;
    __syncthreads();
    float tr = 0.0f;
#pragma unroll
    for (int k = 0; k < GD; ++k) tr += Ym[k][k];
    const float sc = tr * (1.0f / (float)GD);   // ~1.0 for N(0,1) data
    const float inv_sc = 1.0f / sc;
    __syncthreads();                            // all trace reads done
    Ym[i][j] = a * inv_sc;                      // normalized A, eig in ~[0.9,1.1]
    Zm[i][j] = (i == j) ? 1.0f : 0.0f;
    __syncthreads();

    float zn = (i == j) ? 1.0f : 0.0f;
    for (int it = 0; it < 6; ++it) {
        float t = 0.0f;
#pragma unroll
        for (int k = 0; k < GD; ++k) t += Zm[i][k] * Ym[k][j];
        t = ((i == j) ? 1.5f : 0.0f) - 0.5f * t;
        Tm[i][j] = t;
        __syncthreads();
        float yn = 0.0f;
        zn = 0.0f;
#pragma unroll
        for (int k = 0; k < GD; ++k) {
            yn += Ym[i][k] * Tm[k][j];
            zn += Tm[i][k] * Zm[k][j];
        }
        __syncthreads();
        Ym[i][j] = yn;
        Zm[i][j] = zn;
        __syncthreads();
    }
    // W = Z * sc^{-1/2}
    ws[W_OFF + (size_t)((s * NGROUP + g) * GD + i) * GD + j] = zn * rsqrtf(sc);
}

// ---------------- Pass 3: y = (x_gathered - mu) @ W, scattered back ----------------
// block: 256 threads; thread = (g = tid>>2, q = tid&3) owns W[:, q*4..q*4+3] in regs;
// gathers its quad from LDS, rebuilds v[16] via DPP, scatters u[4] to bout.
// (Exact R5/R8/R10 kernel — proven.)
__global__ __launch_bounds__(256, 3) void k_apply(const float* __restrict__ x,
                                                  const int* __restrict__ perms,
                                                  const float* __restrict__ ws,
                                                  float* __restrict__ out) {
    __shared__ float bin[2][C3][D_FEAT];             // 32 KB double-buffered input
    __shared__ float bout[C3][D_FEAT];               // 16 KB output staging
    const int s   = blockIdx.y;
    const int rb  = blockIdx.x;
    const int tid = threadIdx.x;
    const int g   = tid >> 2;
    const int q   = tid & 3;
    const float invB = 1.0f / (float)NB;

    int pcolq[4];
#pragma unroll
    for (int jj = 0; jj < 4; ++jj) pcolq[jj] = perms[s * D_FEAT + tid * 4 + jj];

    // W columns for this thread: w[e][ii] = W[s,g][e][q*4+ii]
    const float* Wp = ws + W_OFF + (size_t)(s * NGROUP + g) * GD * GD;
    float w[GD][4];
#pragma unroll
    for (int e = 0; e < GD; ++e) {
        float4 t4 = *(const float4*)&Wp[e * GD + q * 4];
        w[e][0] = t4.x; w[e][1] = t4.y; w[e][2] = t4.z; w[e][3] = t4.w;
    }
    // bias[ii] = sum_e mu[e] * w[e][ii]  (fold centering into the GEMV)
    float bias[4] = {0.0f, 0.0f, 0.0f, 0.0f};
#pragma unroll
    for (int e = 0; e < GD; ++e) {
        const float mu = ws[SX_OFF + s * D_FEAT + g * GD + e] * invB;
#pragma unroll
        for (int ii = 0; ii < 4; ++ii) bias[ii] += mu * w[e][ii];
    }

    const float* xbase = x + (size_t)(s * NB + rb * RPB3) * D_FEAT;
    float* obase = out + (size_t)(s * NB + rb * RPB3) * D_FEAT;
    constexpr int NCH = RPB3 / C3;                   // 8 chunks

    float4 rr[C3];
#pragma unroll
    for (int t = 0; t < C3; ++t)
        rr[t] = *(const float4*)&xbase[(size_t)t * D_FEAT + tid * 4];

    for (int k = 0; k < NCH; ++k) {
#pragma unroll
        for (int t = 0; t < C3; ++t)
            *(float4*)&bin[k & 1][t][tid * 4] = rr[t];
        __syncthreads();                             // bin[k&1] visible; bout(k-1) stores done
        if (k + 1 < NCH) {                           // prefetch under compute
            const float* nx = xbase + (size_t)(k + 1) * C3 * D_FEAT;
#pragma unroll
            for (int t = 0; t < C3; ++t)
                rr[t] = *(const float4*)&nx[(size_t)t * D_FEAT + tid * 4];
        }
        const float (*cb)[D_FEAT] = bin[k & 1];
#pragma unroll
        for (int r = 0; r < C3; ++r) {
            float vq[4];
#pragma unroll
            for (int jj = 0; jj < 4; ++jj) vq[jj] = cb[r][pcolq[jj]];
            float v[GD];
#pragma unroll
            for (int jj = 0; jj < 4; ++jj) {
                v[0  + jj] = qbc<0>(vq[jj]);
                v[4  + jj] = qbc<1>(vq[jj]);
                v[8  + jj] = qbc<2>(vq[jj]);
                v[12 + jj] = qbc<3>(vq[jj]);
            }
            float u[4] = {-bias[0], -bias[1], -bias[2], -bias[3]};
#pragma unroll
            for (int e = 0; e < GD; ++e)
#pragma unroll
                for (int ii = 0; ii < 4; ++ii) u[ii] = fmaf(v[e], w[e][ii], u[ii]);
#pragma unroll
            for (int ii = 0; ii < 4; ++ii) bout[r][pcolq[ii]] = u[ii];
        }
        __syncthreads();                             // bout complete
        float* ob = obase + (size_t)k * C3 * D_FEAT;
#pragma unroll
        for (int t = 0; t < C3; ++t)
            *(float4*)&ob[(size_t)t * D_FEAT + tid * 4] =
                *(const float4*)&bout[t][tid * 4];
    }
}

extern "C" void kernel_launch(void* const* d_in, const int* in_sizes, int n_in,
                              void* d_out, int out_size, void* d_ws, size_t ws_size,
                              hipStream_t stream) {
    const float* x     = (const float*)d_in[0];
    const int*   perms = (const int*)d_in[1];
    float* out = (float*)d_out;
    float* ws  = (float*)d_ws;

    // bf16-packed partials (768 * 8704 dwords = 26.7 MB) live in d_out:
    // it is 100.7 MB and k_apply fully overwrites every element afterwards.
    uint32_t* part = (uint32_t*)out;

    dim3 g1(P1, NVIEW);                              // 768 blocks = 3/CU
    k_stats_gather<<<g1, 256, 0, stream>>>(x, perms, part);

    dim3 gr1((ENT_DW + 255) / 256, PSPLIT);          // (102, 8)
    k_reduce1<<<gr1, 256, 0, stream>>>(part, ws + RED_OFF);

    k_invsqrt<<<NVIEW * NGROUP, 256, 0, stream>>>(ws + RED_OFF, ws);

    dim3 g3(NB / RPB3, NVIEW);                       // 768 blocks = 3/CU
    k_apply<<<g3, 256, 0, stream>>>(x, perms, ws, out);
}